// Round 1
// baseline (1001.632 us; speedup 1.0000x reference)
//
#include <hip/hip_runtime.h>

// ---------------------------------------------------------------------------
// Fused Swin window attention, bf16 MFMA (16x16x32), one block per window.
// Block = 1024 threads = 16 waves; wave (h,u) = head h, token-half u.
// S computed transposed (S^T = k q^T) so every LDS round-trip writes packed
// b64 (values contiguous along the MFMA C-layout reg axis).
// LDS: xs/os 64x264us (aliased) + per-head {q 64x40, k 64x40, vT 32x72} us,
// P (64x72us) overlays q+k after sync2. Total 152576 B -> 1 block/CU.
// ---------------------------------------------------------------------------

typedef __attribute__((ext_vector_type(8))) short short8;
typedef __attribute__((ext_vector_type(4))) float f4;
typedef __attribute__((ext_vector_type(2))) unsigned int u2v;
typedef __attribute__((ext_vector_type(4))) unsigned int u4v;

#define MFMA16(a, b, c) __builtin_amdgcn_mfma_f32_16x16x32_bf16((a), (b), (c), 0, 0, 0)

__device__ __forceinline__ unsigned int bpack2(float a, float b) {
  unsigned int ua = __float_as_uint(a); ua += 0x7fffu + ((ua >> 16) & 1u);
  unsigned int ub = __float_as_uint(b); ub += 0x7fffu + ((ub >> 16) & 1u);
  return (ua >> 16) | (ub & 0xffff0000u);
}
__device__ __forceinline__ short f2bs(float a) {
  unsigned int u = __float_as_uint(a); u += 0x7fffu + ((u >> 16) & 1u);
  return (short)(u >> 16);
}
__device__ __forceinline__ f4 max4(f4 a, f4 b) {
  f4 r; r[0] = fmaxf(a[0], b[0]); r[1] = fmaxf(a[1], b[1]);
  r[2] = fmaxf(a[2], b[2]); r[3] = fmaxf(a[3], b[3]); return r;
}

// ws layout (bytes):
//   Wall  bf16 [768][256]  @ 0        (393216)  rows: 0-255 q, 256-511 k, 512-767 v
//   Wpb   bf16 [256][256]  @ 393216   (131072)
//   ball  f32  [768]       @ 524288   (3072)
//   biasPT f32 [8][4][4][64][4] @ 527360 (131072)  bias_rel[q][k] at (key-row,query-col) frag order
#define WS_WALL 0
#define WS_WPB 393216
#define WS_BALL 524288
#define WS_BIAS 527360
#define WS_TOTAL 658432

__global__ void prep_kernel(const float* __restrict__ Wq, const float* __restrict__ Wkv,
                            const float* __restrict__ bq, const float* __restrict__ bkv,
                            const float* __restrict__ bt, const float* __restrict__ Wp,
                            short* __restrict__ Wall, short* __restrict__ Wpb,
                            float* __restrict__ ball, float* __restrict__ biasPT) {
  int i = blockIdx.x * 256 + threadIdx.x;
  if (i < 196608) {                       // qkv weights -> bf16 (row-major)
    float v = (i < 65536) ? Wq[i] : Wkv[i - 65536];
    Wall[i] = f2bs(v);
  } else if (i < 262144) {                // out-proj weights -> bf16
    int j = i - 196608;
    Wpb[j] = f2bs(Wp[j]);
  } else if (i < 262912) {                // fused qkv bias
    int j = i - 262144;
    ball[j] = (j < 256) ? bq[j] : bkv[j - 256];
  } else if (i < 295680) {                // relative-position bias, S^T fragment order
    int j = i - 262912;
    int r = j & 3, ln = (j >> 2) & 63, ntq = (j >> 8) & 3, mtk = (j >> 10) & 3, hh = j >> 12;
    int nq = ntq * 16 + (ln & 15);          // query index (column of S^T)
    int mk = mtk * 16 + (ln >> 4) * 4 + r;  // key index   (row of S^T)
    int yi = nq >> 3, xi = nq & 7, yj = mk >> 3, xj = mk & 7;
    int idx = (yi - yj + 7) * 15 + (xi - xj + 7);
    biasPT[j] = bt[idx * 8 + hh];
  }
}

// LDS (ushort units): xs/os [64][264] @0 ; head blob @16896 + h*7424:
//   q [64][40] @+0, k [64][40] @+2560, vT [32][72] @+5120; P [64][72] overlays q/k.
#define LDS_BYTES 152576

__global__ __launch_bounds__(1024) void fused_wattn(
    const float* __restrict__ x, const short* __restrict__ Wall,
    const short* __restrict__ Wpb, const float* __restrict__ ball,
    const float* __restrict__ bp, const float* __restrict__ biasPT,
    const float* __restrict__ mask, float* __restrict__ out) {
  extern __shared__ unsigned short lds[];
  const int b = blockIdx.x;
  const int tid = threadIdx.x;
  const int lane = tid & 63;
  const int wv = tid >> 6;
  const int h = wv >> 1, u = wv & 1;
  const int c = lane & 15, qd = lane >> 4;

  // ---- stage x (64x256 f32) -> bf16 LDS, stride 264 us ----
  {
    const int row = tid >> 4, col = (tid & 15) * 16;
    const float4* src = (const float4*)(x + ((size_t)b * 64 + row) * 256 + col);
    float4 a0 = src[0], a1 = src[1], a2 = src[2], a3 = src[3];
    u4v w0 = {bpack2(a0.x, a0.y), bpack2(a0.z, a0.w), bpack2(a1.x, a1.y), bpack2(a1.z, a1.w)};
    u4v w1 = {bpack2(a2.x, a2.y), bpack2(a2.z, a2.w), bpack2(a3.x, a3.y), bpack2(a3.z, a3.w)};
    u4v* dst = (u4v*)&lds[row * 264 + col];
    dst[0] = w0; dst[1] = w1;
  }
  __syncthreads();  // sync0

  // ---- x fragment cache: wave's token half (rows t = c + 16*(2u+mt2)) ----
  short8 Xf[2][8];
#pragma unroll
  for (int mt2 = 0; mt2 < 2; ++mt2) {
    const unsigned short* px = &lds[(c + 16 * (2 * u + mt2)) * 264 + qd * 8];
#pragma unroll
    for (int ks = 0; ks < 8; ++ks) Xf[mt2][ks] = *(const short8*)(px + ks * 32);
  }
  unsigned short* blob = &lds[16896 + h * 7424];
  const float scale = 0.17677669529663687f;  // 1/sqrt(32)

  // ---- q,k: D[o][t] = W * x^T (A = weight rows, B = x frags) ----
#pragma unroll
  for (int g = 0; g < 2; ++g) {
    unsigned short* dstb = blob + (g == 0 ? 0 : 2560);
#pragma unroll
    for (int mo = 0; mo < 2; ++mo) {
      const short* wr = Wall + (g * 256 + h * 32 + mo * 16 + c) * 256 + qd * 8;
      short8 Wf[8];
#pragma unroll
      for (int ks = 0; ks < 8; ++ks) Wf[ks] = *(const short8*)(wr + ks * 32);
      f4 acc0 = {0.f, 0.f, 0.f, 0.f}, acc1 = {0.f, 0.f, 0.f, 0.f};
#pragma unroll
      for (int ks = 0; ks < 8; ++ks) {
        acc0 = MFMA16(Wf[ks], Xf[0][ks], acc0);
        acc1 = MFMA16(Wf[ks], Xf[1][ks], acc1);
      }
      const f4 bb = *(const f4*)(ball + g * 256 + h * 32 + mo * 16 + qd * 4);
#pragma unroll
      for (int nt2 = 0; nt2 < 2; ++nt2) {
        f4 a = (nt2 ? acc1 : acc0) + bb;
        if (g == 0) a *= scale;
        const int t = 16 * (2 * u + nt2) + c;  // token
        u2v pk = {bpack2(a[0], a[1]), bpack2(a[2], a[3])};
        *(u2v*)&dstb[t * 40 + mo * 16 + qd * 4] = pk;  // [t][d], d contiguous in regs
      }
    }
  }
  // ---- v: D[t][d] = x * W^T (A = x frags, B = weight rows), store vT[d][t] ----
  {
    unsigned short* dstv = blob + 5120;
#pragma unroll
    for (int nd = 0; nd < 2; ++nd) {
      const short* wr = Wall + (512 + h * 32 + nd * 16 + c) * 256 + qd * 8;
      short8 Wf[8];
#pragma unroll
      for (int ks = 0; ks < 8; ++ks) Wf[ks] = *(const short8*)(wr + ks * 32);
      f4 acc0 = {0.f, 0.f, 0.f, 0.f}, acc1 = {0.f, 0.f, 0.f, 0.f};
#pragma unroll
      for (int ks = 0; ks < 8; ++ks) {
        acc0 = MFMA16(Xf[0][ks], Wf[ks], acc0);
        acc1 = MFMA16(Xf[1][ks], Wf[ks], acc1);
      }
      const float bv = ball[512 + h * 32 + nd * 16 + c];
#pragma unroll
      for (int mt2 = 0; mt2 < 2; ++mt2) {
        f4 a = (mt2 ? acc1 : acc0);
        a += bv;
        const int tb = 16 * (2 * u + mt2) + 4 * qd;  // token base, r contiguous
        u2v pk = {bpack2(a[0], a[1]), bpack2(a[2], a[3])};
        *(u2v*)&dstv[(nd * 16 + c) * 72 + tb] = pk;  // vT[d][t]
      }
    }
  }
  __syncthreads();  // sync1: q/k/vT visible to both waves of the head

  // ---- S^T = k q^T (rows = keys, cols = queries) ----
  short8 kf[4], qf[2];
#pragma unroll
  for (int mk = 0; mk < 4; ++mk)
    kf[mk] = *(const short8*)&blob[2560 + (mk * 16 + c) * 40 + qd * 8];
#pragma unroll
  for (int nq = 0; nq < 2; ++nq)
    qf[nq] = *(const short8*)&blob[((2 * u + nq) * 16 + c) * 40 + qd * 8];
  f4 z[4][2];
#pragma unroll
  for (int mk = 0; mk < 4; ++mk)
#pragma unroll
    for (int nq = 0; nq < 2; ++nq) {
      f4 zero = {0.f, 0.f, 0.f, 0.f};
      z[mk][nq] = MFMA16(kf[mk], qf[nq], zero);
    }
  // ---- + relative bias + shift mask (both read in S^T order, float4/lane) ----
  const int w = b & 1023;
  const float* maskw = mask + (size_t)w * 4096;
#pragma unroll
  for (int mk = 0; mk < 4; ++mk)
#pragma unroll
    for (int nq = 0; nq < 2; ++nq) {
      const int ntq = 2 * u + nq;
      f4 bi = *(const f4*)(biasPT + (((h * 4 + mk) * 4 + ntq) * 64 + lane) * 4);
      f4 mv = *(const f4*)(maskw + (ntq * 16 + c) * 64 + mk * 16 + qd * 4);
      z[mk][nq] = z[mk][nq] + bi + mv;
    }
  // ---- softmax over keys (rows of S^T): in-lane 16 + xor16 + xor32 ----
  float cinv[2];
#pragma unroll
  for (int nq = 0; nq < 2; ++nq) {
    f4 m4 = max4(max4(z[0][nq], z[1][nq]), max4(z[2][nq], z[3][nq]));
    float mx = fmaxf(fmaxf(m4[0], m4[1]), fmaxf(m4[2], m4[3]));
    mx = fmaxf(mx, __shfl_xor(mx, 16));
    mx = fmaxf(mx, __shfl_xor(mx, 32));
    f4 s4 = {0.f, 0.f, 0.f, 0.f};
#pragma unroll
    for (int mk = 0; mk < 4; ++mk) {
      f4 e;
      e[0] = __expf(z[mk][nq][0] - mx); e[1] = __expf(z[mk][nq][1] - mx);
      e[2] = __expf(z[mk][nq][2] - mx); e[3] = __expf(z[mk][nq][3] - mx);
      z[mk][nq] = e;
      s4 += e;
    }
    float sm = s4[0] + s4[1] + s4[2] + s4[3];
    sm += __shfl_xor(sm, 16);
    sm += __shfl_xor(sm, 32);
    cinv[nq] = 1.0f / sm;  // folded into P so PV needs no row rescale
  }
  __syncthreads();  // sync2: all q/k reads done before P overlays them

  // ---- P[query][key] bf16 (overlays q+k region), keys contiguous in regs ----
#pragma unroll
  for (int nq = 0; nq < 2; ++nq) {
    const int t = (2 * u + nq) * 16 + c;  // query token (own half -> own rows)
#pragma unroll
    for (int mk = 0; mk < 4; ++mk) {
      f4 p = z[mk][nq] * cinv[nq];
      u2v pk = {bpack2(p[0], p[1]), bpack2(p[2], p[3])};
      *(u2v*)&blob[t * 72 + mk * 16 + qd * 4] = pk;
    }
  }
  // ---- O^T = V^T P^T : A = vT frags, B = P rows ----
  short8 va[2][2], pb[2][2];
#pragma unroll
  for (int ma = 0; ma < 2; ++ma)
#pragma unroll
    for (int kt = 0; kt < 2; ++kt)
      va[ma][kt] = *(const short8*)&blob[5120 + (ma * 16 + c) * 72 + kt * 32 + qd * 8];
#pragma unroll
  for (int nq = 0; nq < 2; ++nq)
#pragma unroll
    for (int kt = 0; kt < 2; ++kt)
      pb[nq][kt] = *(const short8*)&blob[((2 * u + nq) * 16 + c) * 72 + kt * 32 + qd * 8];
  f4 O00 = {0.f, 0.f, 0.f, 0.f}, O01 = O00, O10 = O00, O11 = O00;
#pragma unroll
  for (int kt = 0; kt < 2; ++kt) {
    O00 = MFMA16(va[0][kt], pb[0][kt], O00);
    O01 = MFMA16(va[0][kt], pb[1][kt], O01);
    O10 = MFMA16(va[1][kt], pb[0][kt], O10);
    O11 = MFMA16(va[1][kt], pb[1][kt], O11);
  }
  // ---- write O^T into os[token][h*32+d] (os aliases xs, dead since sync1) ----
#pragma unroll
  for (int nq = 0; nq < 2; ++nq) {
    const int t = (2 * u + nq) * 16 + c;
#pragma unroll
    for (int ma = 0; ma < 2; ++ma) {
      f4 o = (nq == 0) ? (ma == 0 ? O00 : O10) : (ma == 0 ? O01 : O11);
      u2v pk = {bpack2(o[0], o[1]), bpack2(o[2], o[3])};
      *(u2v*)&lds[t * 264 + h * 32 + ma * 16 + qd * 4] = pk;
    }
  }
  __syncthreads();  // sync3: os complete

  // ---- out-proj: D[oc][t] = Wp * os^T, + bp, dwordx4 stores ----
  short8 Bo[2][8];
#pragma unroll
  for (int nt2 = 0; nt2 < 2; ++nt2) {
    const unsigned short* po = &lds[(c + 16 * (2 * u + nt2)) * 264 + qd * 8];
#pragma unroll
    for (int ks = 0; ks < 8; ++ks) Bo[nt2][ks] = *(const short8*)(po + ks * 32);
  }
#pragma unroll
  for (int mo = 0; mo < 2; ++mo) {
    const short* wr = Wpb + (h * 32 + mo * 16 + c) * 256 + qd * 8;
    short8 Wf[8];
#pragma unroll
    for (int ks = 0; ks < 8; ++ks) Wf[ks] = *(const short8*)(wr + ks * 32);
    f4 acc0 = {0.f, 0.f, 0.f, 0.f}, acc1 = {0.f, 0.f, 0.f, 0.f};
#pragma unroll
    for (int ks = 0; ks < 8; ++ks) {
      acc0 = MFMA16(Wf[ks], Bo[0][ks], acc0);
      acc1 = MFMA16(Wf[ks], Bo[1][ks], acc1);
    }
    const f4 bb = *(const f4*)(bp + h * 32 + mo * 16 + qd * 4);
#pragma unroll
    for (int nt2 = 0; nt2 < 2; ++nt2) {
      f4 a = (nt2 ? acc1 : acc0) + bb;
      const int t = 16 * (2 * u + nt2) + c;
      *(f4*)(out + ((size_t)b * 64 + t) * 256 + h * 32 + mo * 16 + qd * 4) = a;
    }
  }
}

extern "C" void kernel_launch(void* const* d_in, const int* in_sizes, int n_in,
                              void* d_out, int out_size, void* d_ws, size_t ws_size,
                              hipStream_t stream) {
  const float* x = (const float*)d_in[0];
  const float* mask = (const float*)d_in[1];
  const float* Wq = (const float*)d_in[2];
  const float* bq = (const float*)d_in[3];
  const float* Wkv = (const float*)d_in[4];
  const float* bkv = (const float*)d_in[5];
  const float* bt = (const float*)d_in[6];
  const float* Wp = (const float*)d_in[7];
  const float* bp = (const float*)d_in[8];
  float* out = (float*)d_out;
  char* ws = (char*)d_ws;

  short* Wall = (short*)(ws + WS_WALL);
  short* Wpb = (short*)(ws + WS_WPB);
  float* ball = (float*)(ws + WS_BALL);
  float* biasPT = (float*)(ws + WS_BIAS);

  prep_kernel<<<1155, 256, 0, stream>>>(Wq, Wkv, bq, bkv, bt, Wp, Wall, Wpb, ball, biasPT);

  (void)hipFuncSetAttribute((const void*)fused_wattn,
                            hipFuncAttributeMaxDynamicSharedMemorySize, LDS_BYTES);
  fused_wattn<<<4096, 1024, LDS_BYTES, stream>>>(x, Wall, Wpb, ball, bp, biasPT, mask, out);
}